// Round 5
// baseline (217.570 us; speedup 1.0000x reference)
//
#include <hip/hip_runtime.h>
#include <cstdint>
#include <cstddef>

#define NB 2048
#define NT 512
#define ND 64
#define NR 50
#define NKK 16
#define REVP 68   // review row stride (floats)

typedef __attribute__((ext_vector_type(8))) short bf16x8;
typedef __attribute__((ext_vector_type(4))) float f32x4;

__device__ inline unsigned short f2bf_rne(float x) {
    unsigned int u = __float_as_uint(x);
    u += 0x7fffu + ((u >> 16) & 1u);
    return (unsigned short)(u >> 16);
}

// split 8 f32 -> hi (truncate) / lo (RNE of remainder), packed as bf16x8
__device__ inline void cvt8_fast(float4 v0, float4 v1, bf16x8& ah, bf16x8& al) {
    float f[8] = {v0.x, v0.y, v0.z, v0.w, v1.x, v1.y, v1.z, v1.w};
    union { unsigned int u[4]; bf16x8 v; } H, L;
#pragma unroll
    for (int p = 0; p < 4; ++p) {
        unsigned int u0 = __float_as_uint(f[2*p]);
        unsigned int u1 = __float_as_uint(f[2*p+1]);
        H.u[p] = (u0 >> 16) | (u1 & 0xffff0000u);
        float r0 = f[2*p]   - __uint_as_float(u0 & 0xffff0000u);
        float r1 = f[2*p+1] - __uint_as_float(u1 & 0xffff0000u);
        unsigned int lp;
        asm("v_cvt_pk_bf16_f32 %0, %1, %2" : "=v"(lp) : "v"(r0), "v"(r1));
        L.u[p] = lp;
    }
    ah = H.v; al = L.v;
}

// ---------------------------------------------------------------------------
// Pack topic_w into main-GEMM B-frag order (hi/lo) and fc weights into
// epilogue B-frag order (K=128: rows 0-63 = fc_r_w, 64-127 = fc_a_w).
__global__ __launch_bounds__(256) void prep_kernel(
    const float* __restrict__ tw,
    const float* __restrict__ fc_u_w, const float* __restrict__ fc_ru_w,
    const float* __restrict__ fc_i_w, const float* __restrict__ fc_ri_w,
    unsigned short* __restrict__ bhi, unsigned short* __restrict__ blo,
    unsigned short* __restrict__ fuhi, unsigned short* __restrict__ fulo,
    unsigned short* __restrict__ fihi, unsigned short* __restrict__ filo)
{
    int i = blockIdx.x * 256 + threadIdx.x;          // 192*256 = 49152
    if (i < 32768) {
        int j  = i & 7;
        int l  = (i >> 3) & 63;
        int n  = (i >> 9) & 3;
        int kk = i >> 11;                            // 0..15
        int t = kk * 32 + ((l >> 4) << 3) + j;
        int d = n * 16 + (l & 15);
        float x = tw[t * ND + d];
        unsigned int u = __float_as_uint(x);
        bhi[i] = (unsigned short)(u >> 16);
        blo[i] = f2bf_rne(x - __uint_as_float(u & 0xffff0000u));
    } else {
        int q = i - 32768;                           // 0..16383
        int br = q >> 13;                            // 0 user, 1 item
        int e = q & 8191;
        int j  = e & 7;
        int l  = (e >> 3) & 63;
        int n  = (e >> 9) & 3;
        int kk = e >> 11;                            // 0..3
        int k = kk * 32 + ((l >> 4) << 3) + j;       // 0..127
        int col = n * 16 + (l & 15);
        const float* W = (k < 64) ? (br ? fc_ri_w : fc_ru_w)
                                  : (br ? fc_i_w  : fc_u_w);
        float x = W[(k & 63) * ND + col];
        unsigned int u = __float_as_uint(x);
        unsigned short hi = (unsigned short)(u >> 16);
        unsigned short lo = f2bf_rne(x - __uint_as_float(u & 0xffff0000u));
        if (br) { fihi[e] = hi; filo[e] = lo; }
        else    { fuhi[e] = hi; fulo[e] = lo; }
    }
}

// ---------------------------------------------------------------------------
__global__ __launch_bounds__(256) void colsum_kernel(const float* __restrict__ tw,
                                                     float* __restrict__ colsum) {
    __shared__ float part[4][ND];
    int d = threadIdx.x & 63, p = threadIdx.x >> 6;
    float s = 0.f;
    for (int t = p; t < NT; t += 4) s += tw[t * ND + d];
    part[p][d] = s;
    __syncthreads();
    if (threadIdx.x < ND)
        colsum[d] = part[0][d] + part[1][d] + part[2][d] + part[3][d];
}

// ---------------------------------------------------------------------------
// One block per (branch, batch element). 4 waves, zero barriers in K-loop:
// A global->reg (depth-2 prefetch, frag layout), B global->reg (L2-resident,
// all 8 loads hoisted per step), MFMA accumulate. LDS only for epilogue.
__global__ __launch_bounds__(256, 4) void branch_kernel(
    const int* __restrict__ user, const int* __restrict__ item,
    const float* __restrict__ user_r_topic, const float* __restrict__ item_r_topic,
    const float* __restrict__ user_embed_w, const float* __restrict__ item_embed_w,
    const float* __restrict__ user_att_w, const float* __restrict__ item_att_w,
    const unsigned short* __restrict__ bhi, const unsigned short* __restrict__ blo,
    const unsigned short* __restrict__ fuhi, const unsigned short* __restrict__ fulo,
    const unsigned short* __restrict__ fihi, const unsigned short* __restrict__ filo,
    const float* __restrict__ fc_u_b, const float* __restrict__ fc_ru_b,
    const float* __restrict__ fc_i_b, const float* __restrict__ fc_ri_b,
    const float* __restrict__ h_u_w, const float* __restrict__ h_u_b,
    const float* __restrict__ h_i_w, const float* __restrict__ h_i_b,
    const float* __restrict__ colsum,
    float* __restrict__ u_vec, float* __restrict__ i_vec)
{
    const int bb = blockIdx.x;
    const int branch = bb >> 11;          // 0 = user, 1 = item
    const int b = bb & (NB - 1);

    const int*   ids     = branch ? item           : user;
    const float* r_topic = branch ? item_r_topic   : user_r_topic;
    const float* emb_w   = branch ? item_embed_w   : user_embed_w;
    const float* att_w   = branch ? item_att_w     : user_att_w;
    const unsigned short* fhi = branch ? fihi : fuhi;
    const unsigned short* flo = branch ? filo : fulo;
    const float* fc_a_b  = branch ? fc_i_b         : fc_u_b;
    const float* fc_r_b  = branch ? fc_ri_b        : fc_ru_b;
    const float* h_w     = branch ? h_i_w          : h_u_w;
    const float* h_b     = branch ? h_i_b          : h_u_b;
    float*       out_vec = branch ? i_vec          : u_vec;

    __shared__ float rev[NR][REVP];       // 13.6 KB
    __shared__ float lds_logit[NR + 2];

    const int tid = threadIdx.x, wave = tid >> 6, lane = tid & 63;
    const int g = lane >> 4, c16 = lane & 15;
    const int id = ids[b];

    const int rowm = wave * 16 + c16;
    const int rowc = rowm < NR ? rowm : NR - 1;
    const float* arow = r_topic + (size_t)b * NR * NT + (size_t)rowc * NT + g * 8;

    f32x4 acc[4];
#pragma unroll
    for (int n = 0; n < 4; ++n) acc[n] = (f32x4){0.f, 0.f, 0.f, 0.f};

    auto gemm_step = [&](int kk, float4& ca, float4& cb, int kn) {
        // B frags for this step: 8 loads, hoisted before the MFMA chain
        const bf16x8* ph = reinterpret_cast<const bf16x8*>(bhi + (size_t)kk * 2048) + lane;
        const bf16x8* pl = reinterpret_cast<const bf16x8*>(blo + (size_t)kk * 2048) + lane;
        bf16x8 bh[4], bl[4];
#pragma unroll
        for (int n = 0; n < 4; ++n) { bh[n] = ph[n * 64]; bl[n] = pl[n * 64]; }
        // A prefetch for step kn (depth 2)
        float4 na = *reinterpret_cast<const float4*>(arow + kn * 32);
        float4 nb = *reinterpret_cast<const float4*>(arow + kn * 32 + 4);
        bf16x8 ah, al;
        cvt8_fast(ca, cb, ah, al);
#pragma unroll
        for (int n = 0; n < 4; ++n) {
            acc[n] = __builtin_amdgcn_mfma_f32_16x16x32_bf16(ah, bh[n], acc[n], 0, 0, 0);
            acc[n] = __builtin_amdgcn_mfma_f32_16x16x32_bf16(al, bh[n], acc[n], 0, 0, 0);
            acc[n] = __builtin_amdgcn_mfma_f32_16x16x32_bf16(ah, bl[n], acc[n], 0, 0, 0);
        }
        ca = na; cb = nb;
    };

    float4 pA = *reinterpret_cast<const float4*>(arow);
    float4 pB = *reinterpret_cast<const float4*>(arow + 4);
    float4 pC = *reinterpret_cast<const float4*>(arow + 32);
    float4 pD = *reinterpret_cast<const float4*>(arow + 36);

#pragma unroll 2
    for (int kk = 0; kk < NKK; kk += 2) {
        gemm_step(kk,     pA, pB, (kk + 2 < NKK ? kk + 2 : NKK - 2));
        gemm_step(kk + 1, pC, pD, (kk + 3 < NKK ? kk + 3 : NKK - 1));
    }

    // C layout: lane holds rows g*4+r4 (within wave tile), col n*16+c16
#pragma unroll
    for (int n = 0; n < 4; ++n)
#pragma unroll
        for (int r4 = 0; r4 < 4; ++r4) {
            int r = wave * 16 + g * 4 + r4;
            if (r < NR) rev[r][n * 16 + c16] = acc[n][r4];
        }
    // no barrier: s-matmul below only reads this wave's own rows (within-wave
    // LDS write->read ordering is handled by compiler lgkmcnt)

    // ---- epilogue s-matmul: s[50x64] = review@fcR + att@fcA (K=128) ----
    f32x4 s4[4];
#pragma unroll
    for (int n = 0; n < 4; ++n) s4[n] = (f32x4){0.f, 0.f, 0.f, 0.f};

#pragma unroll
    for (int kk2 = 0; kk2 < 4; ++kk2) {
        bf16x8 ah, al;
        if (kk2 < 2) {
            const float* rp = &rev[rowc][kk2 * 32 + g * 8];
            cvt8_fast(*reinterpret_cast<const float4*>(rp),
                      *reinterpret_cast<const float4*>(rp + 4), ah, al);
        } else {
            const float* ap = att_w + (size_t)id * ND + (kk2 - 2) * 32 + g * 8;
            cvt8_fast(*reinterpret_cast<const float4*>(ap),
                      *reinterpret_cast<const float4*>(ap + 4), ah, al);
        }
#pragma unroll
        for (int n = 0; n < 4; ++n) {
            const bf16x8* qh = reinterpret_cast<const bf16x8*>(fhi + (size_t)(kk2 * 4 + n) * 512) + lane;
            const bf16x8* ql = reinterpret_cast<const bf16x8*>(flo + (size_t)(kk2 * 4 + n) * 512) + lane;
            bf16x8 bh = *qh, bl = *ql;
            s4[n] = __builtin_amdgcn_mfma_f32_16x16x32_bf16(ah, bh, s4[n], 0, 0, 0);
            s4[n] = __builtin_amdgcn_mfma_f32_16x16x32_bf16(al, bh, s4[n], 0, 0, 0);
            s4[n] = __builtin_amdgcn_mfma_f32_16x16x32_bf16(ah, bl, s4[n], 0, 0, 0);
        }
    }

    // bias + relu + dot with h_w, then 16-lane reduce -> logits
    const float hb = h_b[0];
    float p0 = 0.f, p1 = 0.f, p2 = 0.f, p3 = 0.f;
#pragma unroll
    for (int n = 0; n < 4; ++n) {
        float hwn = h_w[n * 16 + c16];
        float bs = fc_r_b[n * 16 + c16] + fc_a_b[n * 16 + c16];
        p0 = fmaf(fmaxf(s4[n][0] + bs, 0.f), hwn, p0);
        p1 = fmaf(fmaxf(s4[n][1] + bs, 0.f), hwn, p1);
        p2 = fmaf(fmaxf(s4[n][2] + bs, 0.f), hwn, p2);
        p3 = fmaf(fmaxf(s4[n][3] + bs, 0.f), hwn, p3);
    }
#pragma unroll
    for (int off = 1; off < 16; off <<= 1) {
        p0 += __shfl_xor(p0, off);
        p1 += __shfl_xor(p1, off);
        p2 += __shfl_xor(p2, off);
        p3 += __shfl_xor(p3, off);
    }
    if (c16 == 0) {
        int rb = wave * 16 + g * 4;
        if (rb + 0 < NR) lds_logit[rb + 0] = p0 + hb;
        if (rb + 1 < NR) lds_logit[rb + 1] = p1 + hb;
        if (rb + 2 < NR) lds_logit[rb + 2] = p2 + hb;
        if (rb + 3 < NR) lds_logit[rb + 3] = p3 + hb;
    }
    __syncthreads();   // the ONLY barrier: publish rev rows + logits to wave 0

    // softmax + pooling + colsum scale + emb add (wave 0)
    if (wave == 0) {
        float m = -1e30f;
        for (int r = 0; r < NR; ++r) m = fmaxf(m, lds_logit[r]);
        float sum = 0.f;
        for (int r = 0; r < NR; ++r) sum += __expf(lds_logit[r] - m);
        float inv = 1.f / sum;
        float feat = 0.f;
        for (int r = 0; r < NR; ++r)
            feat = fmaf(__expf(lds_logit[r] - m), rev[r][lane], feat);
        feat *= inv;
        out_vec[(size_t)b * ND + lane] = feat * colsum[lane] + emb_w[(size_t)id * ND + lane];
    }
}

// ---------------------------------------------------------------------------
__global__ __launch_bounds__(64) void final_kernel(
    const float* __restrict__ u_vec, const float* __restrict__ i_vec,
    const float* __restrict__ fc_pre_w, const float* __restrict__ fc_pre_b,
    float* __restrict__ out)
{
    int b = blockIdx.x, lane = threadIdx.x;
    float v = u_vec[(size_t)b * ND + lane] * fc_pre_w[lane]
            + i_vec[(size_t)b * ND + lane] * fc_pre_w[ND + lane];
#pragma unroll
    for (int off = 32; off; off >>= 1) v += __shfl_xor(v, off);
    if (lane == 0) out[b] = fmaxf(v + fc_pre_b[0], 0.f);
}

// ---------------------------------------------------------------------------
extern "C" void kernel_launch(void* const* d_in, const int* in_sizes, int n_in,
                              void* d_out, int out_size, void* d_ws, size_t ws_size,
                              hipStream_t stream) {
    (void)in_sizes; (void)n_in; (void)out_size; (void)ws_size;

    const int*   user         = (const int*)d_in[0];
    const int*   item         = (const int*)d_in[1];
    const float* user_r_topic = (const float*)d_in[2];
    const float* item_r_topic = (const float*)d_in[3];
    const float* user_embed_w = (const float*)d_in[4];
    const float* item_embed_w = (const float*)d_in[5];
    const float* user_att_w   = (const float*)d_in[6];
    const float* item_att_w   = (const float*)d_in[7];
    const float* topic_w      = (const float*)d_in[8];
    const float* fc_u_w       = (const float*)d_in[9];
    const float* fc_u_b       = (const float*)d_in[10];
    const float* fc_ru_w      = (const float*)d_in[11];
    const float* fc_ru_b      = (const float*)d_in[12];
    const float* fc_i_w       = (const float*)d_in[13];
    const float* fc_i_b       = (const float*)d_in[14];
    const float* fc_ri_w      = (const float*)d_in[15];
    const float* fc_ri_b      = (const float*)d_in[16];
    const float* h_u_w        = (const float*)d_in[17];
    const float* h_u_b        = (const float*)d_in[18];
    const float* h_i_w        = (const float*)d_in[19];
    const float* h_i_b        = (const float*)d_in[20];
    const float* fc_pre_w     = (const float*)d_in[21];
    const float* fc_pre_b     = (const float*)d_in[22];

    // workspace layout
    unsigned short* bhi  = (unsigned short*)d_ws;      // 32768
    unsigned short* blo  = bhi + 32768;                // 32768
    unsigned short* fuhi = blo + 32768;                // 8192
    unsigned short* fulo = fuhi + 8192;
    unsigned short* fihi = fulo + 8192;
    unsigned short* filo = fihi + 8192;
    float* colsum = (float*)(filo + 8192);             // 64
    float* u_vec  = colsum + 64;                       // NB*ND
    float* i_vec  = u_vec + NB * ND;                   // NB*ND

    prep_kernel<<<192, 256, 0, stream>>>(topic_w, fc_u_w, fc_ru_w, fc_i_w, fc_ri_w,
                                         bhi, blo, fuhi, fulo, fihi, filo);
    colsum_kernel<<<1, 256, 0, stream>>>(topic_w, colsum);

    branch_kernel<<<2 * NB, 256, 0, stream>>>(
        user, item, user_r_topic, item_r_topic,
        user_embed_w, item_embed_w, user_att_w, item_att_w,
        bhi, blo, fuhi, fulo, fihi, filo,
        fc_u_b, fc_ru_b, fc_i_b, fc_ri_b,
        h_u_w, h_u_b, h_i_w, h_i_b,
        colsum, u_vec, i_vec);

    final_kernel<<<NB, 64, 0, stream>>>(u_vec, i_vec, fc_pre_w, fc_pre_b,
                                        (float*)d_out);
}

// Round 6
// 167.365 us; speedup vs baseline: 1.3000x; 1.3000x over previous
//
#include <hip/hip_runtime.h>
#include <cstdint>
#include <cstddef>

#define NB 2048
#define NT 512
#define ND 64
#define NR 50
#define NKK 16
#define REVP 68   // review row stride (floats)

typedef __attribute__((ext_vector_type(8))) short bf16x8;
typedef __attribute__((ext_vector_type(4))) float f32x4;

__device__ inline unsigned short f2bf_rne(float x) {
    unsigned int u = __float_as_uint(x);
    u += 0x7fffu + ((u >> 16) & 1u);
    return (unsigned short)(u >> 16);
}

// split 8 f32 -> hi (truncate) / lo (RNE of remainder), packed as bf16x8
__device__ inline void cvt8_fast(float4 v0, float4 v1, bf16x8& ah, bf16x8& al) {
    float f[8] = {v0.x, v0.y, v0.z, v0.w, v1.x, v1.y, v1.z, v1.w};
    union { unsigned int u[4]; bf16x8 v; } H, L;
#pragma unroll
    for (int p = 0; p < 4; ++p) {
        unsigned int u0 = __float_as_uint(f[2*p]);
        unsigned int u1 = __float_as_uint(f[2*p+1]);
        H.u[p] = (u0 >> 16) | (u1 & 0xffff0000u);
        float r0 = f[2*p]   - __uint_as_float(u0 & 0xffff0000u);
        float r1 = f[2*p+1] - __uint_as_float(u1 & 0xffff0000u);
        unsigned int lp;
        asm("v_cvt_pk_bf16_f32 %0, %1, %2" : "=v"(lp) : "v"(r0), "v"(r1));
        L.u[p] = lp;
    }
    ah = H.v; al = L.v;
}

// ---------------------------------------------------------------------------
// Pack topic_w into main-GEMM B-frag order (hi/lo) and fc weights into
// epilogue B-frag order (K=128: rows 0-63 = fc_r_w, 64-127 = fc_a_w).
__global__ __launch_bounds__(256) void prep_kernel(
    const float* __restrict__ tw,
    const float* __restrict__ fc_u_w, const float* __restrict__ fc_ru_w,
    const float* __restrict__ fc_i_w, const float* __restrict__ fc_ri_w,
    unsigned short* __restrict__ bhi, unsigned short* __restrict__ blo,
    unsigned short* __restrict__ fuhi, unsigned short* __restrict__ fulo,
    unsigned short* __restrict__ fihi, unsigned short* __restrict__ filo)
{
    int i = blockIdx.x * 256 + threadIdx.x;          // 192*256 = 49152
    if (i < 32768) {
        int j  = i & 7;
        int l  = (i >> 3) & 63;
        int n  = (i >> 9) & 3;
        int kk = i >> 11;                            // 0..15
        int t = kk * 32 + ((l >> 4) << 3) + j;
        int d = n * 16 + (l & 15);
        float x = tw[t * ND + d];
        unsigned int u = __float_as_uint(x);
        bhi[i] = (unsigned short)(u >> 16);
        blo[i] = f2bf_rne(x - __uint_as_float(u & 0xffff0000u));
    } else {
        int q = i - 32768;                           // 0..16383
        int br = q >> 13;                            // 0 user, 1 item
        int e = q & 8191;
        int j  = e & 7;
        int l  = (e >> 3) & 63;
        int n  = (e >> 9) & 3;
        int kk = e >> 11;                            // 0..3
        int k = kk * 32 + ((l >> 4) << 3) + j;       // 0..127
        int col = n * 16 + (l & 15);
        const float* W = (k < 64) ? (br ? fc_ri_w : fc_ru_w)
                                  : (br ? fc_i_w  : fc_u_w);
        float x = W[(k & 63) * ND + col];
        unsigned int u = __float_as_uint(x);
        unsigned short hi = (unsigned short)(u >> 16);
        unsigned short lo = f2bf_rne(x - __uint_as_float(u & 0xffff0000u));
        if (br) { fihi[e] = hi; filo[e] = lo; }
        else    { fuhi[e] = hi; fulo[e] = lo; }
    }
}

// ---------------------------------------------------------------------------
__global__ __launch_bounds__(256) void colsum_kernel(const float* __restrict__ tw,
                                                     float* __restrict__ colsum) {
    __shared__ float part[4][ND];
    int d = threadIdx.x & 63, p = threadIdx.x >> 6;
    float s = 0.f;
    for (int t = p; t < NT; t += 4) s += tw[t * ND + d];
    part[p][d] = s;
    __syncthreads();
    if (threadIdx.x < ND)
        colsum[d] = part[0][d] + part[1][d] + part[2][d] + part[3][d];
}

// ---------------------------------------------------------------------------
// One block per (branch, batch-pair). 4 waves, zero barriers in K-loop.
// All-register pipeline: A depth-1 prefetch (2 elems = 2 chains), B-hi
// depth-1 prefetch, B-lo issued at step top / consumed in phase 3.
__global__ __launch_bounds__(256, 3) void branch_kernel(
    const int* __restrict__ user, const int* __restrict__ item,
    const float* __restrict__ user_r_topic, const float* __restrict__ item_r_topic,
    const float* __restrict__ user_embed_w, const float* __restrict__ item_embed_w,
    const float* __restrict__ user_att_w, const float* __restrict__ item_att_w,
    const unsigned short* __restrict__ bhi, const unsigned short* __restrict__ blo,
    const unsigned short* __restrict__ fuhi, const unsigned short* __restrict__ fulo,
    const unsigned short* __restrict__ fihi, const unsigned short* __restrict__ filo,
    const float* __restrict__ fc_u_b, const float* __restrict__ fc_ru_b,
    const float* __restrict__ fc_i_b, const float* __restrict__ fc_ri_b,
    const float* __restrict__ h_u_w, const float* __restrict__ h_u_b,
    const float* __restrict__ h_i_w, const float* __restrict__ h_i_b,
    const float* __restrict__ colsum,
    float* __restrict__ u_vec, float* __restrict__ i_vec)
{
    const int bb = blockIdx.x;
    const int branch = bb >> 10;          // 0 = user, 1 = item
    const int pair = bb & 1023;
    const int b0 = pair * 2, b1 = b0 + 1;

    const int*   ids     = branch ? item           : user;
    const float* r_topic = branch ? item_r_topic   : user_r_topic;
    const float* emb_w   = branch ? item_embed_w   : user_embed_w;
    const float* att_w   = branch ? item_att_w     : user_att_w;
    const unsigned short* fhi = branch ? fihi : fuhi;
    const unsigned short* flo = branch ? filo : fulo;
    const float* fc_a_b  = branch ? fc_i_b         : fc_u_b;
    const float* fc_r_b  = branch ? fc_ri_b        : fc_ru_b;
    const float* h_w     = branch ? h_i_w          : h_u_w;
    const float* h_b     = branch ? h_i_b          : h_u_b;
    float*       out_vec = branch ? i_vec          : u_vec;

    __shared__ float rev[2][NR][REVP];    // 27.2 KB
    __shared__ float lds_logit[2][NR + 2];

    const int tid = threadIdx.x, wave = tid >> 6, lane = tid & 63;
    const int g = lane >> 4, c16 = lane & 15;
    const int id0 = ids[b0], id1 = ids[b1];

    const int rowm = wave * 16 + c16;
    const int rowc = rowm < NR ? rowm : NR - 1;
    const float* arow0 = r_topic + (size_t)b0 * NR * NT + (size_t)rowc * NT + g * 8;
    const float* arow1 = arow0 + (size_t)NR * NT;

    f32x4 acc0[4], acc1[4];
#pragma unroll
    for (int n = 0; n < 4; ++n) {
        acc0[n] = (f32x4){0.f, 0.f, 0.f, 0.f};
        acc1[n] = (f32x4){0.f, 0.f, 0.f, 0.f};
    }

    // ---- preload: B-hi frags of step 0, A chunks of step 0 ----
    bf16x8 BH[4];
#pragma unroll
    for (int n = 0; n < 4; ++n)
        BH[n] = *(reinterpret_cast<const bf16x8*>(bhi) + n * 64 + lane);
    float4 c00 = *reinterpret_cast<const float4*>(arow0);
    float4 c01 = *reinterpret_cast<const float4*>(arow0 + 4);
    float4 c10 = *reinterpret_cast<const float4*>(arow1);
    float4 c11 = *reinterpret_cast<const float4*>(arow1 + 4);

#pragma unroll 2
    for (int kk = 0; kk < NKK; ++kk) {
        const int kn = (kk + 1 < NKK) ? kk + 1 : NKK - 1;
        // B-lo of THIS step: issued now, consumed in phase 3 (latency covered)
        bf16x8 BL[4];
#pragma unroll
        for (int n = 0; n < 4; ++n)
            BL[n] = *(reinterpret_cast<const bf16x8*>(blo + (size_t)kk * 2048) + n * 64 + lane);
        // B-hi of NEXT step (depth-1 prefetch)
        bf16x8 BHn[4];
#pragma unroll
        for (int n = 0; n < 4; ++n)
            BHn[n] = *(reinterpret_cast<const bf16x8*>(bhi + (size_t)kn * 2048) + n * 64 + lane);
        // A of NEXT step (depth-1 prefetch, 2 independent streams)
        float4 n00 = *reinterpret_cast<const float4*>(arow0 + kn * 32);
        float4 n01 = *reinterpret_cast<const float4*>(arow0 + kn * 32 + 4);
        float4 n10 = *reinterpret_cast<const float4*>(arow1 + kn * 32);
        float4 n11 = *reinterpret_cast<const float4*>(arow1 + kn * 32 + 4);

        bf16x8 ah0, al0, ah1, al1;
        cvt8_fast(c00, c01, ah0, al0);
        cvt8_fast(c10, c11, ah1, al1);

        // phase 1: ah * BH (BH prefetched last step -> ready)
#pragma unroll
        for (int n = 0; n < 4; ++n) {
            acc0[n] = __builtin_amdgcn_mfma_f32_16x16x32_bf16(ah0, BH[n], acc0[n], 0, 0, 0);
            acc1[n] = __builtin_amdgcn_mfma_f32_16x16x32_bf16(ah1, BH[n], acc1[n], 0, 0, 0);
        }
        // phase 2: al * BH
#pragma unroll
        for (int n = 0; n < 4; ++n) {
            acc0[n] = __builtin_amdgcn_mfma_f32_16x16x32_bf16(al0, BH[n], acc0[n], 0, 0, 0);
            acc1[n] = __builtin_amdgcn_mfma_f32_16x16x32_bf16(al1, BH[n], acc1[n], 0, 0, 0);
        }
        // phase 3: ah * BL (BL issued ~16 MFMAs ago)
#pragma unroll
        for (int n = 0; n < 4; ++n) {
            acc0[n] = __builtin_amdgcn_mfma_f32_16x16x32_bf16(ah0, BL[n], acc0[n], 0, 0, 0);
            acc1[n] = __builtin_amdgcn_mfma_f32_16x16x32_bf16(ah1, BL[n], acc1[n], 0, 0, 0);
        }
#pragma unroll
        for (int n = 0; n < 4; ++n) BH[n] = BHn[n];
        c00 = n00; c01 = n01; c10 = n10; c11 = n11;
    }

    // C layout: lane holds rows g*4+r4 (within wave tile), col n*16+c16
#pragma unroll
    for (int n = 0; n < 4; ++n)
#pragma unroll
        for (int r4 = 0; r4 < 4; ++r4) {
            int r = wave * 16 + g * 4 + r4;
            if (r < NR) {
                rev[0][r][n * 16 + c16] = acc0[n][r4];
                rev[1][r][n * 16 + c16] = acc1[n][r4];
            }
        }
    // no barrier: epilogue reads only this wave's own rows

    // ---- epilogue s-matmul: s[50x64] = review@fcR + att@fcA (K=128) ----
    f32x4 s40[4], s41[4];
#pragma unroll
    for (int n = 0; n < 4; ++n) {
        s40[n] = (f32x4){0.f, 0.f, 0.f, 0.f};
        s41[n] = (f32x4){0.f, 0.f, 0.f, 0.f};
    }

#pragma unroll
    for (int kk2 = 0; kk2 < 4; ++kk2) {
        bf16x8 ah0, al0, ah1, al1;
        if (kk2 < 2) {
            const float* rp0 = &rev[0][rowc][kk2 * 32 + g * 8];
            const float* rp1 = &rev[1][rowc][kk2 * 32 + g * 8];
            cvt8_fast(*reinterpret_cast<const float4*>(rp0),
                      *reinterpret_cast<const float4*>(rp0 + 4), ah0, al0);
            cvt8_fast(*reinterpret_cast<const float4*>(rp1),
                      *reinterpret_cast<const float4*>(rp1 + 4), ah1, al1);
        } else {
            const float* ap0 = att_w + (size_t)id0 * ND + (kk2 - 2) * 32 + g * 8;
            const float* ap1 = att_w + (size_t)id1 * ND + (kk2 - 2) * 32 + g * 8;
            cvt8_fast(*reinterpret_cast<const float4*>(ap0),
                      *reinterpret_cast<const float4*>(ap0 + 4), ah0, al0);
            cvt8_fast(*reinterpret_cast<const float4*>(ap1),
                      *reinterpret_cast<const float4*>(ap1 + 4), ah1, al1);
        }
#pragma unroll
        for (int n = 0; n < 4; ++n) {
            bf16x8 bh = *(reinterpret_cast<const bf16x8*>(fhi + (size_t)(kk2 * 4 + n) * 512) + lane);
            bf16x8 bl = *(reinterpret_cast<const bf16x8*>(flo + (size_t)(kk2 * 4 + n) * 512) + lane);
            s40[n] = __builtin_amdgcn_mfma_f32_16x16x32_bf16(ah0, bh, s40[n], 0, 0, 0);
            s40[n] = __builtin_amdgcn_mfma_f32_16x16x32_bf16(al0, bh, s40[n], 0, 0, 0);
            s40[n] = __builtin_amdgcn_mfma_f32_16x16x32_bf16(ah0, bl, s40[n], 0, 0, 0);
            s41[n] = __builtin_amdgcn_mfma_f32_16x16x32_bf16(ah1, bh, s41[n], 0, 0, 0);
            s41[n] = __builtin_amdgcn_mfma_f32_16x16x32_bf16(al1, bh, s41[n], 0, 0, 0);
            s41[n] = __builtin_amdgcn_mfma_f32_16x16x32_bf16(ah1, bl, s41[n], 0, 0, 0);
        }
    }

    // bias + relu + dot with h_w, then 16-lane reduce -> logits (both elems)
    const float hb = h_b[0];
    {
        float p0 = 0.f, p1 = 0.f, p2 = 0.f, p3 = 0.f;
        float q0 = 0.f, q1 = 0.f, q2 = 0.f, q3 = 0.f;
#pragma unroll
        for (int n = 0; n < 4; ++n) {
            float hwn = h_w[n * 16 + c16];
            float bs = fc_r_b[n * 16 + c16] + fc_a_b[n * 16 + c16];
            p0 = fmaf(fmaxf(s40[n][0] + bs, 0.f), hwn, p0);
            p1 = fmaf(fmaxf(s40[n][1] + bs, 0.f), hwn, p1);
            p2 = fmaf(fmaxf(s40[n][2] + bs, 0.f), hwn, p2);
            p3 = fmaf(fmaxf(s40[n][3] + bs, 0.f), hwn, p3);
            q0 = fmaf(fmaxf(s41[n][0] + bs, 0.f), hwn, q0);
            q1 = fmaf(fmaxf(s41[n][1] + bs, 0.f), hwn, q1);
            q2 = fmaf(fmaxf(s41[n][2] + bs, 0.f), hwn, q2);
            q3 = fmaf(fmaxf(s41[n][3] + bs, 0.f), hwn, q3);
        }
#pragma unroll
        for (int off = 1; off < 16; off <<= 1) {
            p0 += __shfl_xor(p0, off); p1 += __shfl_xor(p1, off);
            p2 += __shfl_xor(p2, off); p3 += __shfl_xor(p3, off);
            q0 += __shfl_xor(q0, off); q1 += __shfl_xor(q1, off);
            q2 += __shfl_xor(q2, off); q3 += __shfl_xor(q3, off);
        }
        if (c16 == 0) {
            int rb = wave * 16 + g * 4;
            if (rb + 0 < NR) { lds_logit[0][rb + 0] = p0 + hb; lds_logit[1][rb + 0] = q0 + hb; }
            if (rb + 1 < NR) { lds_logit[0][rb + 1] = p1 + hb; lds_logit[1][rb + 1] = q1 + hb; }
            if (rb + 2 < NR) { lds_logit[0][rb + 2] = p2 + hb; lds_logit[1][rb + 2] = q2 + hb; }
            if (rb + 3 < NR) { lds_logit[0][rb + 3] = p3 + hb; lds_logit[1][rb + 3] = q3 + hb; }
        }
    }
    __syncthreads();   // the ONLY barrier: publish rev + logits

    // softmax + pooling + colsum scale + emb add (wave 0 -> b0, wave 1 -> b1)
    if (wave < 2) {
        const int bi = wave;
        const int b = bi ? b1 : b0;
        const int id = bi ? id1 : id0;
        float m = -1e30f;
        for (int r = 0; r < NR; ++r) m = fmaxf(m, lds_logit[bi][r]);
        float sum = 0.f;
        for (int r = 0; r < NR; ++r) sum += __expf(lds_logit[bi][r] - m);
        float inv = 1.f / sum;
        float feat = 0.f;
        for (int r = 0; r < NR; ++r)
            feat = fmaf(__expf(lds_logit[bi][r] - m), rev[bi][r][lane], feat);
        feat *= inv;
        out_vec[(size_t)b * ND + lane] = feat * colsum[lane] + emb_w[(size_t)id * ND + lane];
    }
}

// ---------------------------------------------------------------------------
__global__ __launch_bounds__(64) void final_kernel(
    const float* __restrict__ u_vec, const float* __restrict__ i_vec,
    const float* __restrict__ fc_pre_w, const float* __restrict__ fc_pre_b,
    float* __restrict__ out)
{
    int b = blockIdx.x, lane = threadIdx.x;
    float v = u_vec[(size_t)b * ND + lane] * fc_pre_w[lane]
            + i_vec[(size_t)b * ND + lane] * fc_pre_w[ND + lane];
#pragma unroll
    for (int off = 32; off; off >>= 1) v += __shfl_xor(v, off);
    if (lane == 0) out[b] = fmaxf(v + fc_pre_b[0], 0.f);
}

// ---------------------------------------------------------------------------
extern "C" void kernel_launch(void* const* d_in, const int* in_sizes, int n_in,
                              void* d_out, int out_size, void* d_ws, size_t ws_size,
                              hipStream_t stream) {
    (void)in_sizes; (void)n_in; (void)out_size; (void)ws_size;

    const int*   user         = (const int*)d_in[0];
    const int*   item         = (const int*)d_in[1];
    const float* user_r_topic = (const float*)d_in[2];
    const float* item_r_topic = (const float*)d_in[3];
    const float* user_embed_w = (const float*)d_in[4];
    const float* item_embed_w = (const float*)d_in[5];
    const float* user_att_w   = (const float*)d_in[6];
    const float* item_att_w   = (const float*)d_in[7];
    const float* topic_w      = (const float*)d_in[8];
    const float* fc_u_w       = (const float*)d_in[9];
    const float* fc_u_b       = (const float*)d_in[10];
    const float* fc_ru_w      = (const float*)d_in[11];
    const float* fc_ru_b      = (const float*)d_in[12];
    const float* fc_i_w       = (const float*)d_in[13];
    const float* fc_i_b       = (const float*)d_in[14];
    const float* fc_ri_w      = (const float*)d_in[15];
    const float* fc_ri_b      = (const float*)d_in[16];
    const float* h_u_w        = (const float*)d_in[17];
    const float* h_u_b        = (const float*)d_in[18];
    const float* h_i_w        = (const float*)d_in[19];
    const float* h_i_b        = (const float*)d_in[20];
    const float* fc_pre_w     = (const float*)d_in[21];
    const float* fc_pre_b     = (const float*)d_in[22];

    // workspace layout
    unsigned short* bhi  = (unsigned short*)d_ws;      // 32768
    unsigned short* blo  = bhi + 32768;                // 32768
    unsigned short* fuhi = blo + 32768;                // 8192
    unsigned short* fulo = fuhi + 8192;
    unsigned short* fihi = fulo + 8192;
    unsigned short* filo = fihi + 8192;
    float* colsum = (float*)(filo + 8192);             // 64
    float* u_vec  = colsum + 64;                       // NB*ND
    float* i_vec  = u_vec + NB * ND;                   // NB*ND

    prep_kernel<<<192, 256, 0, stream>>>(topic_w, fc_u_w, fc_ru_w, fc_i_w, fc_ri_w,
                                         bhi, blo, fuhi, fulo, fihi, filo);
    colsum_kernel<<<1, 256, 0, stream>>>(topic_w, colsum);

    branch_kernel<<<2 * (NB / 2), 256, 0, stream>>>(
        user, item, user_r_topic, item_r_topic,
        user_embed_w, item_embed_w, user_att_w, item_att_w,
        bhi, blo, fuhi, fulo, fihi, filo,
        fc_u_b, fc_ru_b, fc_i_b, fc_ri_b,
        h_u_w, h_u_b, h_i_w, h_i_b,
        colsum, u_vec, i_vec);

    final_kernel<<<NB, 64, 0, stream>>>(u_vec, i_vec, fc_pre_w, fc_pre_b,
                                        (float*)d_out);
}